// Round 1
// baseline (39.259 us; speedup 1.0000x reference)
//
#include <hip/hip_runtime.h>

#define HEADS 8
#define NTOK 4096
#define CH 128
#define KSPLIT 8
#define KCHUNK (NTOK / KSPLIT)   // 512
#define ROWS 32                  // rows per ln_qk block
#define LN_EPS 1e-5f

typedef short short8 __attribute__((ext_vector_type(8)));
typedef short short4v __attribute__((ext_vector_type(4)));
typedef float f32x4 __attribute__((ext_vector_type(4)));
typedef float f32x2 __attribute__((ext_vector_type(2)));

__device__ inline unsigned short f2bf(float f) {
    unsigned int u = __float_as_uint(f);
    u = (u + 0x7FFFu + ((u >> 16) & 1u)) >> 16;
    return (unsigned short)u;
}

__device__ inline float fast_exp2(float x) {
#if __has_builtin(__builtin_amdgcn_exp2f)
    return __builtin_amdgcn_exp2f(x);
#else
    float r; asm volatile("v_exp_f32 %0, %1" : "=v"(r) : "v"(x)); return r;
#endif
}

// packed f32 fma: lowers to v_pk_fma_f32 (VOP3P) when available
__device__ inline f32x2 fma2(f32x2 a, f32x2 b, f32x2 c) {
#if __has_builtin(__builtin_elementwise_fma)
    return __builtin_elementwise_fma(a, b, c);
#else
    f32x2 r; r.x = fmaf(a.x, b.x, c.x); r.y = fmaf(a.y, b.y, c.y); return r;
#endif
}

// 16x16x16 bf16 MFMA (K=16 exactly). Fallback: zero-padded 16x16x32 —
// identical contraction since A and B pad the same k positions.
__device__ inline f32x4 mfma16(short4v a, short4v b, f32x4 c) {
#if __has_builtin(__builtin_amdgcn_mfma_f32_16x16x16bf16_1k)
    return __builtin_amdgcn_mfma_f32_16x16x16bf16_1k(a, b, c, 0, 0, 0);
#elif __has_builtin(__builtin_amdgcn_mfma_f32_16x16x16_bf16)
    return __builtin_amdgcn_mfma_f32_16x16x16_bf16(a, b, c, 0, 0, 0);
#else
    short8 a8 = {a.x, a.y, a.z, a.w, (short)0, (short)0, (short)0, (short)0};
    short8 b8 = {b.x, b.y, b.z, b.w, (short)0, (short)0, (short)0, (short)0};
    return __builtin_amdgcn_mfma_f32_16x16x32_bf16(a8, b8, c, 0, 0, 0);
#endif
}

// softmax scale * log2(e), folded into q columns of W
#define SC (0.08838834764831845f * 1.4426950408889634f)

// ---------------------------------------------------------------------------
// Kernel A: LayerNorm + QK projection via MFMA, W-fragments built inline.
// Block = 32 rows x 4 waves; blockIdx.y = ct-group of 4; wave w owns
// ct = ctg*4 + w (ct<8 -> q head ct, ct>=8 -> k head ct-8).
// LDS tile is XOR-swizzled (c ^= (row&7)<<3 in shorts) to break the 16-way
// bank conflict on the ds_read_b128 A-fragment reads (row stride = 256 B).
// y==0 blocks additionally transpose A -> vT[h][n] for the attention kernel.
// ---------------------------------------------------------------------------
__global__ __launch_bounds__(256) void ln_qk_fused(
    const float* __restrict__ x, const float* __restrict__ Wqk,
    const float* __restrict__ g, const float* __restrict__ b,
    const float* __restrict__ A,
    unsigned short* __restrict__ qb, unsigned short* __restrict__ kbuf,
    float* __restrict__ vT)
{
    __shared__ __align__(16) unsigned short xn_s[ROWS][CH];   // bf16, 8 KB
    const int tid = threadIdx.x;
    const int wave = tid >> 6, lane = tid & 63;
    const int row0 = blockIdx.x * ROWS;
    const int ct = blockIdx.y * 4 + wave;
    const int j = lane & 15, grp = lane >> 4;

    // Build B-fragments for this ct directly from W (L2-resident, 128 KB).
    // wf[ks]: lane holds W[ks*32 + grp*8 + jj][ct*16 + j], jj = 0..7.
    const float sc = (ct < 8) ? SC : 1.0f;
    short8 wf[4];
    #pragma unroll
    for (int ks = 0; ks < 4; ++ks) {
        unsigned int uu0, uu1, uu2, uu3;
        const float* wp = Wqk + (ks * 32 + grp * 8) * 256 + ct * 16 + j;
        uu0 = f2bf(wp[0 * 256] * sc) | ((unsigned)f2bf(wp[1 * 256] * sc) << 16);
        uu1 = f2bf(wp[2 * 256] * sc) | ((unsigned)f2bf(wp[3 * 256] * sc) << 16);
        uu2 = f2bf(wp[4 * 256] * sc) | ((unsigned)f2bf(wp[5 * 256] * sc) << 16);
        uu3 = f2bf(wp[6 * 256] * sc) | ((unsigned)f2bf(wp[7 * 256] * sc) << 16);
        uint4 packed = {uu0, uu1, uu2, uu3};
        wf[ks] = *(short8*)&packed;
    }

    // A transpose side-task (one ct-group is enough): vT[h][n] = A[n][h]
    if (blockIdx.y == 0) {
        const int hh = tid >> 5, r = tid & 31;
        vT[hh * NTOK + row0 + r] = A[(size_t)(row0 + r) * HEADS + hh];
    }

    // LayerNorm: each wave handles 8 rows, 2 elements/lane
    for (int rr = wave; rr < ROWS; rr += 4) {
        const int row = row0 + rr;
        float2 xv = *(const float2*)(x + row * CH + lane * 2);
        float s  = xv.x + xv.y;
        float sq = xv.x * xv.x + xv.y * xv.y;
        #pragma unroll
        for (int off = 32; off >= 1; off >>= 1) {
            s  += __shfl_xor(s, off);
            sq += __shfl_xor(sq, off);
        }
        float mu  = s * (1.0f / CH);
        float var = sq * (1.0f / CH) - mu * mu;
        float rs  = rsqrtf(var + LN_EPS);
        float2 gv = *(const float2*)(g + lane * 2);
        float2 bv = *(const float2*)(b + lane * 2);
        unsigned int lo = f2bf((xv.x - mu) * rs * gv.x + bv.x);
        unsigned int hi = f2bf((xv.y - mu) * rs * gv.y + bv.y);
        const int c = (lane * 2) ^ ((rr & 7) << 3);      // swizzled column
        *(unsigned int*)&xn_s[rr][c] = lo | (hi << 16);
    }
    __syncthreads();

    // Two 16-row tiles per block, reusing wf
    #pragma unroll
    for (int t = 0; t < 2; ++t) {
        // A-fragments: lane holds xn[row = t*16 + j][ks*32 + grp*8 + jj]
        short8 af[4];
        #pragma unroll
        for (int ks = 0; ks < 4; ++ks)
            af[ks] = *(const short8*)(&xn_s[t * 16 + j]
                                          [(ks * 32 + grp * 8) ^ ((j & 7) << 3)]);

        f32x4 acc = {0.f, 0.f, 0.f, 0.f};
        #pragma unroll
        for (int ks = 0; ks < 4; ++ks)
            acc = __builtin_amdgcn_mfma_f32_16x16x32_bf16(af[ks], wf[ks], acc, 0, 0, 0);

        // C/D layout: row = grp*4 + r, col = j
        unsigned short* dst = (ct < 8)
            ? qb   + ((size_t)ct * NTOK + row0 + t * 16) * 16
            : kbuf + ((size_t)(ct - 8) * NTOK + row0 + t * 16) * 16;
        #pragma unroll
        for (int r = 0; r < 4; ++r)
            dst[(grp * 4 + r) * 16 + j] = f2bf(acc[r]);
    }
}

// ---------------------------------------------------------------------------
// Kernel B: MFMA attention partials, S^T orientation (K = A-op, Q = B-op),
// 16x16x16 shape (K dim = hd = 16 exactly, no zero-padded lanes).
// Wave owns 32 queries (2 tiles); all 4 waves of a block share one
// (head, 512-key chunk) K stream. Lane (grp,j): score for key m+grp*4+r, q=j.
// E/F accumulate as packed f32x2 (v_pk_add/v_pk_fma); v comes from the
// pre-transposed vT as a single float4 per iter.
// Prefetches intentionally over-run the chunk by one iter: workspace layout
// (qb, kbuf, vT, partE, partF) keeps those dead loads in mapped memory.
// ---------------------------------------------------------------------------
__global__ __launch_bounds__(256) void attn_kernel(
    const unsigned short* __restrict__ qb, const unsigned short* __restrict__ kbuf,
    const float* __restrict__ vT,
    float* __restrict__ partE, float* __restrict__ partF)
{
    const int tid = threadIdx.x;
    const int wave = tid >> 6, lane = tid & 63;
    const int ksp = blockIdx.y, h = blockIdx.z;
    const int q0 = blockIdx.x * 128 + wave * 32;
    const int m0 = ksp * KCHUNK;
    const int j = lane & 15, grp = lane >> 4;

    // Q as B-operand (16x16x16): lane holds Q[q0+j][kd = grp*4 .. +4]
    short4v qf0 = *(const short4v*)(qb + ((size_t)(h * NTOK + q0 + j) * 16 + grp * 4));
    short4v qf1 = *(const short4v*)(qb + ((size_t)(h * NTOK + q0 + 16 + j) * 16 + grp * 4));

    // K as A-operand: lane holds K[m + j][kd = grp*4 .. +4]
    const unsigned short* kl = kbuf + ((size_t)(h * NTOK + m0 + j) * 16 + grp * 4);
    const float* vl = vT + h * NTOK + m0 + grp * 4;

    f32x2 E0 = {0.f, 0.f}, F0 = {0.f, 0.f};
    f32x2 E1 = {0.f, 0.f}, F1 = {0.f, 0.f};

    short4v kf = *(const short4v*)kl;
    f32x4 vv = *(const f32x4*)vl;

    #pragma unroll 4
    for (int mi = 0; mi < KCHUNK; mi += 16) {
        short4v kn = *(const short4v*)(kl + (size_t)(mi + 16) * 16);
        f32x4 vn = *(const f32x4*)(vl + mi + 16);

        f32x4 z = {0.f, 0.f, 0.f, 0.f};
        f32x4 s0 = mfma16(kf, qf0, z);   // s[key = grp*4+r][q = j]
        f32x4 s1 = mfma16(kf, qf1, z);   // queries q0+16..q0+31

        f32x2 p01, p23, r01, r23;
        p01.x = fast_exp2(s0[0]); p01.y = fast_exp2(s0[1]);
        p23.x = fast_exp2(s0[2]); p23.y = fast_exp2(s0[3]);
        r01.x = fast_exp2(s1[0]); r01.y = fast_exp2(s1[1]);
        r23.x = fast_exp2(s1[2]); r23.y = fast_exp2(s1[3]);

        E0 += p01 + p23;
        F0 = fma2(p01, vv.xy, F0);
        F0 = fma2(p23, vv.zw, F0);
        E1 += r01 + r23;
        F1 = fma2(r01, vv.xy, F1);
        F1 = fma2(r23, vv.zw, F1);

        kf = kn; vv = vn;
    }

    float e0 = E0.x + E0.y, f0 = F0.x + F0.y;
    float e1 = E1.x + E1.y, f1 = F1.x + F1.y;

    // reduce across the 4 lane-groups (keys are partitioned by grp)
    #pragma unroll
    for (int off = 16; off < 64; off <<= 1) {
        e0 += __shfl_xor(e0, off);
        f0 += __shfl_xor(f0, off);
        e1 += __shfl_xor(e1, off);
        f1 += __shfl_xor(f1, off);
    }

    if (lane < 16) {
        const int base = (ksp * HEADS + h) * NTOK;
        partE[base + q0 + j]      = e0;
        partF[base + q0 + j]      = f0;
        partE[base + q0 + 16 + j] = e1;
        partF[base + q0 + 16 + j] = f1;
    }
}

// ---------------------------------------------------------------------------
// Kernel C: reduce k-splits, out = A + wv * F / E
// ---------------------------------------------------------------------------
__global__ __launch_bounds__(256) void reduce_kernel(
    const float* __restrict__ partE, const float* __restrict__ partF,
    const float* __restrict__ A, const float* __restrict__ Wv,
    float* __restrict__ out)
{
    const int t = blockIdx.x * 256 + threadIdx.x;   // 0..32767
    const int n = t >> 3;
    const int h = t & 7;
    float E = 0.f, F = 0.f;
    #pragma unroll
    for (int s = 0; s < KSPLIT; ++s) {
        E += partE[(s * HEADS + h) * NTOK + n];
        F += partF[(s * HEADS + h) * NTOK + n];
    }
    out[t] = A[t] + Wv[0] * F / E;
}

// ---------------------------------------------------------------------------
extern "C" void kernel_launch(void* const* d_in, const int* in_sizes, int n_in,
                              void* d_out, int out_size, void* d_ws, size_t ws_size,
                              hipStream_t stream)
{
    const float* x   = (const float*)d_in[0];
    const float* A   = (const float*)d_in[1];
    const float* Wqk = (const float*)d_in[2];
    const float* Wv  = (const float*)d_in[3];
    const float* g   = (const float*)d_in[4];
    const float* b   = (const float*)d_in[5];
    float* out = (float*)d_out;

    // Order matters: attn's dead last-iteration prefetch runs ~0.5 KB past
    // kbuf (lands in vT) and ~64 B past vT (lands in partE) — mapped either way.
    unsigned short* qb   = (unsigned short*)d_ws;                  // 1 MB
    unsigned short* kbuf = qb + (size_t)HEADS * NTOK * 16;         // 1 MB
    float* vT    = (float*)(kbuf + (size_t)HEADS * NTOK * 16);     // 128 KB
    float* partE = vT + (size_t)HEADS * NTOK;                      // 1 MB
    float* partF = partE + (size_t)KSPLIT * HEADS * NTOK;          // 1 MB

    ln_qk_fused<<<dim3(NTOK / ROWS, 4), dim3(256), 0, stream>>>(
        x, Wqk, g, b, A, qb, kbuf, vT);
    attn_kernel<<<dim3(NTOK / 128, KSPLIT, HEADS), dim3(256), 0, stream>>>(
        qb, kbuf, vT, partE, partF);
    reduce_kernel<<<dim3(NTOK * HEADS / 256), dim3(256), 0, stream>>>(
        partE, partF, A, Wv, out);
}